// Round 10
// baseline (238.165 us; speedup 1.0000x reference)
//
#include <hip/hip_runtime.h>

// Frame-wise E^H D E exact NDFT via separable phasors as two complex GEMMs on
// fp16 matrix cores (fp32 accumulate).
// v11 = v10 (234.0us best) + ONE change: Ey materialized TILED-only.
//  - Ey table layout [t][kt16][yc8][kp128][yq16] (same tiling as ExC).
//    fwd epilogue reads it as contiguous 1KB wave-loads (v5 pattern; the
//    v6 linear layout cost ~15us in 64x-scattered 16B reads -- v5/v6 ledger).
//    adj build reads are by-broadcast (one 32B transaction) in either layout,
//    so adj is unaffected; its body stays v10-verbatim.
//  - fwd main loop / adj / preps otherwise v10 verbatim. ws stays 58MB.

#define NT 16
#define NK 2048
#define NXY 128
#define NC 8

typedef _Float16 f16x8 __attribute__((ext_vector_type(8)));
typedef float f32x4 __attribute__((ext_vector_type(4)));

union F8 { f16x8 h; uint u[4]; };

#define MFMA16(a, b, c) __builtin_amdgcn_mfma_f32_16x16x32_f16((a), (b), (c), 0, 0, 0)

__device__ __forceinline__ uint pack2h(float a, float b) {
    union { _Float16 h[2]; uint u; } p;
    p.h[0] = (_Float16)a; p.h[1] = (_Float16)b;
    return p.u;
}
__device__ __forceinline__ float2 unpack2h(uint v) {
    union { uint u; _Float16 h[2]; } p;
    p.u = v;
    return make_float2((float)p.h[0], (float)p.h[1]);
}
__device__ __forceinline__ uint rot16(uint v) { return (v >> 16) | (v << 16); }

// ---------------------------------------------------------------------------
// prep_phasA: tiled ExC [t][kt16][xc8][kp128][xq16] (fwd B) and tiled EyC
// (same layout; fwd epilogue + adj build). exp(-i*k*(coord-64)).
// ---------------------------------------------------------------------------
__global__ __launch_bounds__(256) void prep_phasA(const float* __restrict__ ktraj,
                                                  uint* __restrict__ ExC,
                                                  uint* __restrict__ EyC) {
    const int t = blockIdx.x;
    const int k = blockIdx.y * 2 + (threadIdx.x >> 7);
    const int x = threadIdx.x & 127;
    const float kx = ktraj[(size_t)k * NT + t];
    const float ky = ktraj[(size_t)(NK + k) * NT + t];
    const float xm = (float)(x - 64);
    const size_t off = ((size_t)(t * 16 + (k >> 7)) * 8 + (x >> 4)) * 2048 +
                       (size_t)(k & 127) * 16 + (x & 15);
    float s, c;
    __sincosf(-kx * xm, &s, &c);
    ExC[off] = pack2h(c, s);
    __sincosf(-ky * xm, &s, &c);
    EyC[off] = pack2h(c, s);
}

// ---------------------------------------------------------------------------
// ExT[t][x][k]; lanes = k -> contiguous 1KB store runs. (adj B-loads)
// ---------------------------------------------------------------------------
__global__ __launch_bounds__(256) void prep_phasB(const float* __restrict__ ktraj,
                                                  uint* __restrict__ ExT) {
    const int t = blockIdx.x, x = blockIdx.y;
    const int k = blockIdx.z * 256 + threadIdx.x;
    const float kx = ktraj[(size_t)k * NT + t];
    float s, c;
    __sincosf(-kx * (float)(x - 64), &s, &c);
    ExT[((size_t)t * NXY + x) * NK + k] = pack2h(c, s);
}

// ---------------------------------------------------------------------------
// srcB in MFMA-fragment order: [t][c][ch8][mf8][r16][xl16] dwords,
// element = smap[c,x,y]*img[x,y,t], x = ch*16+xl, y = mf*16+r.
// ---------------------------------------------------------------------------
__global__ __launch_bounds__(256) void prep_src(const float* __restrict__ xin,
                                                const float* __restrict__ csmap,
                                                uint* __restrict__ srcB) {
    const int idx = blockIdx.x * 256 + threadIdx.x;   // < 2^21
    const int t = idx & 15, r = (idx >> 4) & 15, xl = (idx >> 8) & 15,
              mf = (idx >> 12) & 7, ch = (idx >> 15) & 7, c = idx >> 18;
    const int x = ch * 16 + xl, y = mf * 16 + r;
    const float ir = xin[(size_t)(x * NXY + y) * NT + t];
    const float ii = xin[(size_t)NXY * NXY * NT + (size_t)(x * NXY + y) * NT + t];
    const float sr = csmap[(size_t)c * 2 * NXY * NXY + x * NXY + y];
    const float si = csmap[(size_t)c * 2 * NXY * NXY + NXY * NXY + x * NXY + y];
    srcB[((size_t)(t * NC + c) << 14) + ch * 2048 + mf * 256 + r * 16 + xl] =
        pack2h(sr * ir - si * ii, sr * ii + si * ir);
}

// ---------------------------------------------------------------------------
// fwd_gemm: block = (t, c, kt of 64 kpoints), 256 thr (4 waves: 2 mh x 2 nq).
// C1[y=128, kp=64] over K'=256, 8 chunks. Fragment-ordered LDS A, B + A
// prefetched one chunk ahead in registers, B-side complex rotation.
// v11: epilogue reads TILED EyC -> contiguous 1KB wave-loads.
// ---------------------------------------------------------------------------
__global__ __launch_bounds__(256, 2) void fwd_gemm(const uint* __restrict__ ExC,
                                                   const uint* __restrict__ EyC,
                                                   const uint* __restrict__ srcB,
                                                   const float* __restrict__ dcomp,
                                                   float2* __restrict__ g) {
    const int t = blockIdx.x, c = blockIdx.y, kt = blockIdx.z;
    const int tid = threadIdx.x, lane = tid & 63, ws = tid >> 6;
    const int quad = lane >> 4, l15 = lane & 15;
    const int mh = ws >> 1, nq = ws & 1;

    __shared__ __align__(16) _Float16 As[2][4096];

    f32x4 accr[4][2], acci[4][2];
#pragma unroll
    for (int mf = 0; mf < 4; ++mf)
#pragma unroll
        for (int nf = 0; nf < 2; ++nf) { accr[mf][nf] = (f32x4)0.0f; acci[mf][nf] = (f32x4)0.0f; }

    const uint* srcT = srcB + ((size_t)(t * NC + c) << 14);
    const uint* exB = ExC + (size_t)(t * 16 + (kt >> 1)) * 16384;
    const int kin0 = (kt & 1) * 64 + nq * 32;            // kp base within 128-tile

    // prologue: stage + B loads for chunk 0
    F8 vA0 = *(const F8*)(srcT + tid * 8);
    F8 vA1 = *(const F8*)(srcT + tid * 8 + 4);
    F8 Bc0 = *(const F8*)(exB + (kin0 + l15) * 16 + quad * 4);
    F8 Bc1 = *(const F8*)(exB + (kin0 + 16 + l15) * 16 + quad * 4);

#pragma unroll 2
    for (int ch = 0; ch < 8; ++ch) {
        const int buf = ch & 1;
        *(F8*)&As[buf][tid * 16] = vA0;
        *(F8*)&As[buf][tid * 16 + 8] = vA1;
        __syncthreads();
        const int chn = ch < 7 ? ch + 1 : 7;
        vA0 = *(const F8*)(srcT + chn * 2048 + tid * 8);
        vA1 = *(const F8*)(srcT + chn * 2048 + tid * 8 + 4);
        F8 Bn0 = *(const F8*)(exB + chn * 2048 + (kin0 + l15) * 16 + quad * 4);
        F8 Bn1 = *(const F8*)(exB + chn * 2048 + (kin0 + 16 + l15) * 16 + quad * 4);
        __builtin_amdgcn_sched_barrier(0);
        // B-side rotation: Br = (bR,-bI) for real part, Bi = (bI,bR) for imag
        F8 Br0, Bi0, Br1, Bi1;
#pragma unroll
        for (int d = 0; d < 4; ++d) {
            Br0.u[d] = Bc0.u[d] ^ 0x80000000u;
            Bi0.u[d] = rot16(Bc0.u[d]);
            Br1.u[d] = Bc1.u[d] ^ 0x80000000u;
            Bi1.u[d] = rot16(Bc1.u[d]);
        }
#pragma unroll
        for (int mf = 0; mf < 4; ++mf) {
            F8 Ap = *(const F8*)&As[buf][(mh * 4 + mf) * 512 + l15 * 32 + quad * 8];
            accr[mf][0] = MFMA16(Ap.h, Br0.h, accr[mf][0]);
            acci[mf][0] = MFMA16(Ap.h, Bi0.h, acci[mf][0]);
            accr[mf][1] = MFMA16(Ap.h, Br1.h, accr[mf][1]);
            acci[mf][1] = MFMA16(Ap.h, Bi1.h, acci[mf][1]);
        }
        Bc0 = Bn0; Bc1 = Bn1;
    }

    // epilogue: partial y-reduction with tiled EyC (contiguous 1KB wave-loads)
    __syncthreads();
    float* red = (float*)(&As[0][0]);
    const uint* eyB = EyC + (size_t)(t * 16 + (kt >> 1)) * 16384;
#pragma unroll
    for (int nf = 0; nf < 2; ++nf) {
        const int kin = kin0 + nf * 16 + l15;                   // kp within 128-tile
        float kdr = 0.f, kdi = 0.f;
#pragma unroll
        for (int mf = 0; mf < 4; ++mf) {
            const int yc = mh * 4 + mf;
            F8 e4 = *(const F8*)(eyB + yc * 2048 + kin * 16 + quad * 4);
#pragma unroll
            for (int rr = 0; rr < 4; ++rr) {
                float2 ey = unpack2h(e4.u[rr]);
                float cr = accr[mf][nf][rr], ci = acci[mf][nf][rr];
                kdr += ey.x * cr - ey.y * ci;
                kdi += ey.x * ci + ey.y * cr;
            }
        }
        kdr += __shfl_xor(kdr, 16); kdr += __shfl_xor(kdr, 32);
        kdi += __shfl_xor(kdi, 16); kdi += __shfl_xor(kdi, 32);
        if (lane < 16) {
            const int kl = nq * 32 + nf * 16 + l15;       // 0..63
            red[(mh * 64 + kl) * 2] = kdr;
            red[(mh * 64 + kl) * 2 + 1] = kdi;
        }
    }
    __syncthreads();
    if (tid < 64) {
        const int kpoint = kt * 64 + tid;
        const float kdr = red[tid * 2] + red[(64 + tid) * 2];
        const float kdi = red[tid * 2 + 1] + red[(64 + tid) * 2 + 1];
        const float w = dcomp[(size_t)kpoint * NT + t] * (1.0f / 16384.0f);
        g[((size_t)t * NK + kpoint) * NC + c] = make_float2(kdr * w, kdi * w);
    }
}

// ---------------------------------------------------------------------------
// adj_gemm: block = (t, ytile of 8 y), 512 thr (8 waves).  (v10 body; the only
// change is the Ey build read indexing the tiled EyC -- same transaction
// count: address depends only on by, 8-lane broadcast of 32B.)
// ---------------------------------------------------------------------------
__global__ __launch_bounds__(512) void adj_gemm(const uint* __restrict__ ExT,
                                                const uint* __restrict__ EyC,
                                                const float2* __restrict__ g,
                                                const float* __restrict__ csmap,
                                                float* __restrict__ out) {
    const int t = blockIdx.x, yt = blockIdx.y, ybase = yt * 8;
    const int tid = threadIdx.x, lane = tid & 63, ws = tid >> 6;
    const int quad = lane >> 4, l15 = lane & 15;
    const int x = ws * 16 + l15;

    __shared__ __align__(16) _Float16 Ts[2][64][72];    // 64 K'-halves + 8 pad

    f32x4 accr[4], acci[4];
#pragma unroll
    for (int mf = 0; mf < 4; ++mf) { accr[mf] = (f32x4)0.0f; acci[mf] = (f32x4)0.0f; }

    const float2* gBase = g + (size_t)t * NK * NC;
    const uint* eyT = EyC + (size_t)t * 262144;          // tiled [kt][yc][kp][yq]
    const uint* exRow = ExT + (size_t)t * NXY * NK + (size_t)x * NK;

    const int bm = tid & 63;                 // build: row m
    const int bk4 = (tid >> 6) * 4;          // build: kpoint offset (0..28)
    const int by = ybase + (bm >> 3), bc = bm & 7;
    const int ybank = (by >> 4) * 2048 + (by & 15);

    // build chunk 0
    {
        F8 w;
#pragma unroll
        for (int j = 0; j < 4; ++j) {
            int kp = bk4 + j;
            float2 gv = gBase[kp * NC + bc];
            float2 ey = unpack2h(eyT[(size_t)kp * 16 + ybank]);   // kt=0 tile
            w.u[j] = pack2h(ey.x * gv.x + ey.y * gv.y, ey.x * gv.y - ey.y * gv.x);
        }
        *(F8*)&Ts[0][bm][bk4 * 2] = w;
    }
    __syncthreads();

    for (int ch = 0; ch < 64; ++ch) {
        const int buf = ch & 1;
        const int chn = ch < 63 ? ch + 1 : 63;       // clamped: last iter redundant
        // --- issue ALL global loads for this iteration up front ---
        const int kb = chn * 32 + bk4;
        const uint* eyKt = eyT + (size_t)(kb >> 7) * 16384 + ybank;
        const int kpl = kb & 127;
        float2 gv0 = gBase[(kb + 0) * NC + bc];
        float2 gv1 = gBase[(kb + 1) * NC + bc];
        float2 gv2 = gBase[(kb + 2) * NC + bc];
        float2 gv3 = gBase[(kb + 3) * NC + bc];
        uint ev0 = eyKt[(size_t)(kpl + 0) * 16];
        uint ev1 = eyKt[(size_t)(kpl + 1) * 16];
        uint ev2 = eyKt[(size_t)(kpl + 2) * 16];
        uint ev3 = eyKt[(size_t)(kpl + 3) * 16];
        F8 Bf0 = *(const F8*)(exRow + ch * 32 + quad * 4);
        F8 Bf1 = *(const F8*)(exRow + ch * 32 + 16 + quad * 4);
        // B-side rotation for imag accumulator: Bi = (-bI, bR)
        F8 Bi0, Bi1;
#pragma unroll
        for (int d = 0; d < 4; ++d) {
            Bi0.u[d] = rot16(Bf0.u[d]) ^ 0x00008000u;
            Bi1.u[d] = rot16(Bf1.u[d]) ^ 0x00008000u;
        }
        // --- MFMA phase on Ts[buf] ---
#pragma unroll
        for (int mf = 0; mf < 4; ++mf) {
            F8 Ap0 = *(const F8*)&Ts[buf][mf * 16 + l15][quad * 8];
            accr[mf] = MFMA16(Ap0.h, Bf0.h, accr[mf]);
            acci[mf] = MFMA16(Ap0.h, Bi0.h, acci[mf]);
            F8 Ap1 = *(const F8*)&Ts[buf][mf * 16 + l15][32 + quad * 8];
            accr[mf] = MFMA16(Ap1.h, Bf1.h, accr[mf]);
            acci[mf] = MFMA16(Ap1.h, Bi1.h, acci[mf]);
        }
        // --- pack + write build for chunk ch+1 ---
        {
            F8 w; float2 e;
            e = unpack2h(ev0); w.u[0] = pack2h(e.x*gv0.x + e.y*gv0.y, e.x*gv0.y - e.y*gv0.x);
            e = unpack2h(ev1); w.u[1] = pack2h(e.x*gv1.x + e.y*gv1.y, e.x*gv1.y - e.y*gv1.x);
            e = unpack2h(ev2); w.u[2] = pack2h(e.x*gv2.x + e.y*gv2.y, e.x*gv2.y - e.y*gv2.x);
            e = unpack2h(ev3); w.u[3] = pack2h(e.x*gv3.x + e.y*gv3.y, e.x*gv3.y - e.y*gv3.x);
            *(F8*)&Ts[buf ^ 1][bm][bk4 * 2] = w;
        }
        __syncthreads();
    }

    // epilogue: coil-combine with conj(smap), write out[2][x][y][t]
#pragma unroll
    for (int mf = 0; mf < 4; ++mf) {
        const int y = ybase + 2 * mf + (quad >> 1);
        float or_ = 0.f, oi_ = 0.f;
#pragma unroll
        for (int r = 0; r < 4; ++r) {
            int c = 4 * (quad & 1) + r;
            float sr = csmap[(size_t)c * 2 * NXY * NXY + x * NXY + y];
            float si = csmap[(size_t)c * 2 * NXY * NXY + NXY * NXY + x * NXY + y];
            float xr = accr[mf][r], xi = acci[mf][r];
            or_ += sr * xr + si * xi;
            oi_ += sr * xi - si * xr;
        }
        or_ += __shfl_xor(or_, 16);
        oi_ += __shfl_xor(oi_, 16);
        if ((lane & 16) == 0) {
            out[(size_t)(x * NXY + y) * NT + t] = or_;
            out[(size_t)NXY * NXY * NT + (size_t)(x * NXY + y) * NT + t] = oi_;
        }
    }
}

// ---------------------------------------------------------------------------
extern "C" void kernel_launch(void* const* d_in, const int* in_sizes, int n_in,
                              void* d_out, int out_size, void* d_ws, size_t ws_size,
                              hipStream_t stream) {
    const float* xin   = (const float*)d_in[0];  // (2,128,128,16)
    const float* ktraj = (const float*)d_in[1];  // (2,2048,16)
    const float* csmap = (const float*)d_in[2];  // (8,2,128,128)
    const float* dcomp = (const float*)d_in[3];  // (2048,16)
    float* out = (float*)d_out;                  // (2,128,128,16)

    // ws layout: ExC + ExT + EyC (16MB each) + srcB 8MB + g 2MB = 58MB
    const size_t TBL = (size_t)NT * NK * NXY;            // 4.19M dwords per table
    uint* ExC  = (uint*)d_ws;                            // [t][kt][xc][kp][xq]
    uint* ExT  = ExC + TBL;                              // [t][x][k]
    uint* EyC  = ExT + TBL;                              // [t][kt][yc][kp][yq]
    uint* srcB = EyC + TBL;                              // fragment-ordered
    float2* g  = (float2*)(srcB + (size_t)NT * NC * NXY * NXY);  // [t][k][c]

    prep_phasA<<<dim3(NT, NK / 2), 256, 0, stream>>>(ktraj, ExC, EyC);
    prep_phasB<<<dim3(NT, NXY, NK / 256), 256, 0, stream>>>(ktraj, ExT);
    prep_src<<<dim3(8192), 256, 0, stream>>>(xin, csmap, srcB);
    fwd_gemm<<<dim3(NT, NC, 32), 256, 0, stream>>>(ExC, EyC, srcB, dcomp, g);
    adj_gemm<<<dim3(NT, NXY / 8), 512, 0, stream>>>(ExT, EyC, g, csmap, out);
}

// Round 11
// 221.271 us; speedup vs baseline: 1.0763x; 1.0763x over previous
//
#include <hip/hip_runtime.h>

// Frame-wise E^H D E exact NDFT via separable phasors as two complex GEMMs on
// fp16 matrix cores (fp32 accumulate).
// v12 = v10 (234.0us best) with:
//  - adj_gemm: v10 VERBATIM (92.0us measured; v11's tiled-Ey addressing sank
//    the prefetch loads, VGPR 56->40, +5.6us -> reverted to linear EyL).
//  - fwd_gemm: B-duplication removed. 4 waves each own a DISTINCT 16-kp slice
//    and all 8 mf rows: 1 B-load/chunk/wave (B traffic halves), same MFMA
//    count, same 64 acc VGPRs; epilogue fully in-wave (no LDS combine pass).
//  - preps fused into ONE kernel (branch on block range, per-branch code
//    identical): removes 2 launch gaps, co-schedules independent preps.

#define NT 16
#define NK 2048
#define NXY 128
#define NC 8

typedef _Float16 f16x8 __attribute__((ext_vector_type(8)));
typedef float f32x4 __attribute__((ext_vector_type(4)));

union F8 { f16x8 h; uint u[4]; };

#define MFMA16(a, b, c) __builtin_amdgcn_mfma_f32_16x16x32_f16((a), (b), (c), 0, 0, 0)

__device__ __forceinline__ uint pack2h(float a, float b) {
    union { _Float16 h[2]; uint u; } p;
    p.h[0] = (_Float16)a; p.h[1] = (_Float16)b;
    return p.u;
}
__device__ __forceinline__ float2 unpack2h(uint v) {
    union { uint u; _Float16 h[2]; } p;
    p.u = v;
    return make_float2((float)p.h[0], (float)p.h[1]);
}
__device__ __forceinline__ uint rot16(uint v) { return (v >> 16) | (v << 16); }

// ---------------------------------------------------------------------------
// prep_all: fused preps, branch on block range (block-uniform divergence).
//  [0, 16384):      phasA -> tiled ExC [t][kt16][xc8][kp128][xq16] + linear
//                   EyL [t][k][y]
//  [16384, 32768):  phasB -> ExT [t][x][k]
//  [32768, 40960):  src   -> srcB fragment order [t][c][ch8][mf8][r16][xl16]
// ---------------------------------------------------------------------------
__global__ __launch_bounds__(256) void prep_all(const float* __restrict__ ktraj,
                                                const float* __restrict__ xin,
                                                const float* __restrict__ csmap,
                                                uint* __restrict__ ExC,
                                                uint* __restrict__ ExT,
                                                uint* __restrict__ EyL,
                                                uint* __restrict__ srcB) {
    const int b = blockIdx.x;
    const int tid = threadIdx.x;
    if (b < 16384) {
        // ---- phasA ----
        const int t = b >> 10;
        const int k = (b & 1023) * 2 + (tid >> 7);
        const int x = tid & 127;
        const float kx = ktraj[(size_t)k * NT + t];
        const float ky = ktraj[(size_t)(NK + k) * NT + t];
        const float xm = (float)(x - 64);
        float s, c;
        __sincosf(-kx * xm, &s, &c);
        ExC[((size_t)(t * 16 + (k >> 7)) * 8 + (x >> 4)) * 2048 +
            (size_t)(k & 127) * 16 + (x & 15)] = pack2h(c, s);
        __sincosf(-ky * xm, &s, &c);
        EyL[((size_t)t * NK + k) * NXY + x] = pack2h(c, s);
    } else if (b < 32768) {
        // ---- phasB ----
        const int q = b - 16384;
        const int t = q >> 10, x = (q >> 3) & 127, kz = q & 7;
        const int k = kz * 256 + tid;
        const float kx = ktraj[(size_t)k * NT + t];
        float s, c;
        __sincosf(-kx * (float)(x - 64), &s, &c);
        ExT[((size_t)t * NXY + x) * NK + k] = pack2h(c, s);
    } else {
        // ---- src ----
        const int idx = (b - 32768) * 256 + tid;   // < 2^21
        const int t = idx & 15, r = (idx >> 4) & 15, xl = (idx >> 8) & 15,
                  mf = (idx >> 12) & 7, ch = (idx >> 15) & 7, c = idx >> 18;
        const int x = ch * 16 + xl, y = mf * 16 + r;
        const float ir = xin[(size_t)(x * NXY + y) * NT + t];
        const float ii = xin[(size_t)NXY * NXY * NT + (size_t)(x * NXY + y) * NT + t];
        const float sr = csmap[(size_t)c * 2 * NXY * NXY + x * NXY + y];
        const float si = csmap[(size_t)c * 2 * NXY * NXY + NXY * NXY + x * NXY + y];
        srcB[((size_t)(t * NC + c) << 14) + ch * 2048 + mf * 256 + r * 16 + xl] =
            pack2h(sr * ir - si * ii, sr * ii + si * ir);
    }
}

// ---------------------------------------------------------------------------
// fwd_gemm: block = (t, c, kt of 64 kpoints), 256 thr, 4 waves.
// v12 partition: wave ws owns kp slice [kt*64 + ws*16, +16) and ALL 8 mf rows.
// Per chunk per wave: 1 B-load (no duplication), 8 LDS A-fragments, 16 MFMA.
// acc 8x2x4 = 64 VGPR. Epilogue fully in-wave: y-reduce over its 8 mf with
// EyL, quad-reduce via shfl, direct g store. B-side complex rotation.
// ---------------------------------------------------------------------------
__global__ __launch_bounds__(256, 2) void fwd_gemm(const uint* __restrict__ ExC,
                                                   const uint* __restrict__ EyL,
                                                   const uint* __restrict__ srcB,
                                                   const float* __restrict__ dcomp,
                                                   float2* __restrict__ g) {
    const int t = blockIdx.x, c = blockIdx.y, kt = blockIdx.z;
    const int tid = threadIdx.x, lane = tid & 63, ws = tid >> 6;
    const int quad = lane >> 4, l15 = lane & 15;

    __shared__ __align__(16) _Float16 As[2][4096];

    f32x4 accr[8], acci[8];
#pragma unroll
    for (int mf = 0; mf < 8; ++mf) { accr[mf] = (f32x4)0.0f; acci[mf] = (f32x4)0.0f; }

    const uint* srcT = srcB + ((size_t)(t * NC + c) << 14);
    const uint* exB = ExC + (size_t)(t * 16 + (kt >> 1)) * 16384;
    const int kin0 = (kt & 1) * 64 + ws * 16;            // this wave's kp base (128-tile)

    // prologue: stage + B load for chunk 0
    F8 vA0 = *(const F8*)(srcT + tid * 8);
    F8 vA1 = *(const F8*)(srcT + tid * 8 + 4);
    F8 Bc = *(const F8*)(exB + (kin0 + l15) * 16 + quad * 4);

#pragma unroll 2
    for (int ch = 0; ch < 8; ++ch) {
        const int buf = ch & 1;
        *(F8*)&As[buf][tid * 16] = vA0;
        *(F8*)&As[buf][tid * 16 + 8] = vA1;
        __syncthreads();
        const int chn = ch < 7 ? ch + 1 : 7;
        vA0 = *(const F8*)(srcT + chn * 2048 + tid * 8);
        vA1 = *(const F8*)(srcT + chn * 2048 + tid * 8 + 4);
        F8 Bn = *(const F8*)(exB + chn * 2048 + (kin0 + l15) * 16 + quad * 4);
        __builtin_amdgcn_sched_barrier(0);
        // B-side rotation: Br = (bR,-bI) for real part, Bi = (bI,bR) for imag
        F8 Br, Bi;
#pragma unroll
        for (int d = 0; d < 4; ++d) {
            Br.u[d] = Bc.u[d] ^ 0x80000000u;
            Bi.u[d] = rot16(Bc.u[d]);
        }
#pragma unroll
        for (int mf = 0; mf < 8; ++mf) {
            F8 Ap = *(const F8*)&As[buf][mf * 512 + l15 * 32 + quad * 8];
            accr[mf] = MFMA16(Ap.h, Br.h, accr[mf]);
            acci[mf] = MFMA16(Ap.h, Bi.h, acci[mf]);
        }
        Bc = Bn;
    }

    // epilogue: in-wave y-reduction with EyL (all 8 mf), quad-reduce, store g
    const int kpoint = kt * 64 + ws * 16 + l15;
    const uint* eyRow = EyL + ((size_t)t * NK + kpoint) * NXY;
    float kdr = 0.f, kdi = 0.f;
#pragma unroll
    for (int mf = 0; mf < 8; ++mf) {
        F8 e4 = *(const F8*)(eyRow + mf * 16 + quad * 4);
#pragma unroll
        for (int rr = 0; rr < 4; ++rr) {
            float2 ey = unpack2h(e4.u[rr]);
            float cr = accr[mf][rr], ci = acci[mf][rr];
            kdr += ey.x * cr - ey.y * ci;
            kdi += ey.x * ci + ey.y * cr;
        }
    }
    kdr += __shfl_xor(kdr, 16); kdr += __shfl_xor(kdr, 32);
    kdi += __shfl_xor(kdi, 16); kdi += __shfl_xor(kdi, 32);
    if (lane < 16) {
        float w = dcomp[(size_t)kpoint * NT + t] * (1.0f / 16384.0f);
        g[((size_t)t * NK + kpoint) * NC + c] = make_float2(kdr * w, kdi * w);
    }
}

// ---------------------------------------------------------------------------
// adj_gemm: block = (t, ytile of 8 y), 512 thr (8 waves).  (v10 body VERBATIM:
// straight-line loads first, B-side rotation, pack after MFMA, linear EyL.)
// ---------------------------------------------------------------------------
__global__ __launch_bounds__(512) void adj_gemm(const uint* __restrict__ ExT,
                                                const uint* __restrict__ EyL,
                                                const float2* __restrict__ g,
                                                const float* __restrict__ csmap,
                                                float* __restrict__ out) {
    const int t = blockIdx.x, yt = blockIdx.y, ybase = yt * 8;
    const int tid = threadIdx.x, lane = tid & 63, ws = tid >> 6;
    const int quad = lane >> 4, l15 = lane & 15;
    const int x = ws * 16 + l15;

    __shared__ __align__(16) _Float16 Ts[2][64][72];    // 64 K'-halves + 8 pad

    f32x4 accr[4], acci[4];
#pragma unroll
    for (int mf = 0; mf < 4; ++mf) { accr[mf] = (f32x4)0.0f; acci[mf] = (f32x4)0.0f; }

    const float2* gBase = g + (size_t)t * NK * NC;
    const uint* eyBase = EyL + (size_t)t * NK * NXY;
    const uint* exRow = ExT + (size_t)t * NXY * NK + (size_t)x * NK;

    const int bm = tid & 63;                 // build: row m
    const int bk4 = (tid >> 6) * 4;          // build: kpoint offset (0..28)
    const int by = ybase + (bm >> 3), bc = bm & 7;

    // build chunk 0
    {
        F8 w;
#pragma unroll
        for (int j = 0; j < 4; ++j) {
            int kp = bk4 + j;
            float2 gv = gBase[kp * NC + bc];
            float2 ey = unpack2h(eyBase[(size_t)kp * NXY + by]);
            w.u[j] = pack2h(ey.x * gv.x + ey.y * gv.y, ey.x * gv.y - ey.y * gv.x);
        }
        *(F8*)&Ts[0][bm][bk4 * 2] = w;
    }
    __syncthreads();

    for (int ch = 0; ch < 64; ++ch) {
        const int buf = ch & 1;
        const int chn = ch < 63 ? ch + 1 : 63;       // clamped: last iter redundant
        // --- issue ALL global loads for this iteration up front ---
        const int kb = chn * 32 + bk4;
        float2 gv0 = gBase[(kb + 0) * NC + bc];
        float2 gv1 = gBase[(kb + 1) * NC + bc];
        float2 gv2 = gBase[(kb + 2) * NC + bc];
        float2 gv3 = gBase[(kb + 3) * NC + bc];
        uint ev0 = eyBase[(size_t)(kb + 0) * NXY + by];
        uint ev1 = eyBase[(size_t)(kb + 1) * NXY + by];
        uint ev2 = eyBase[(size_t)(kb + 2) * NXY + by];
        uint ev3 = eyBase[(size_t)(kb + 3) * NXY + by];
        F8 Bf0 = *(const F8*)(exRow + ch * 32 + quad * 4);
        F8 Bf1 = *(const F8*)(exRow + ch * 32 + 16 + quad * 4);
        // B-side rotation for imag accumulator: Bi = (-bI, bR)
        F8 Bi0, Bi1;
#pragma unroll
        for (int d = 0; d < 4; ++d) {
            Bi0.u[d] = rot16(Bf0.u[d]) ^ 0x00008000u;
            Bi1.u[d] = rot16(Bf1.u[d]) ^ 0x00008000u;
        }
        // --- MFMA phase on Ts[buf] ---
#pragma unroll
        for (int mf = 0; mf < 4; ++mf) {
            F8 Ap0 = *(const F8*)&Ts[buf][mf * 16 + l15][quad * 8];
            accr[mf] = MFMA16(Ap0.h, Bf0.h, accr[mf]);
            acci[mf] = MFMA16(Ap0.h, Bi0.h, acci[mf]);
            F8 Ap1 = *(const F8*)&Ts[buf][mf * 16 + l15][32 + quad * 8];
            accr[mf] = MFMA16(Ap1.h, Bf1.h, accr[mf]);
            acci[mf] = MFMA16(Ap1.h, Bi1.h, acci[mf]);
        }
        // --- pack + write build for chunk ch+1 ---
        {
            F8 w; float2 e;
            e = unpack2h(ev0); w.u[0] = pack2h(e.x*gv0.x + e.y*gv0.y, e.x*gv0.y - e.y*gv0.x);
            e = unpack2h(ev1); w.u[1] = pack2h(e.x*gv1.x + e.y*gv1.y, e.x*gv1.y - e.y*gv1.x);
            e = unpack2h(ev2); w.u[2] = pack2h(e.x*gv2.x + e.y*gv2.y, e.x*gv2.y - e.y*gv2.x);
            e = unpack2h(ev3); w.u[3] = pack2h(e.x*gv3.x + e.y*gv3.y, e.x*gv3.y - e.y*gv3.x);
            *(F8*)&Ts[buf ^ 1][bm][bk4 * 2] = w;
        }
        __syncthreads();
    }

    // epilogue: coil-combine with conj(smap), write out[2][x][y][t]
#pragma unroll
    for (int mf = 0; mf < 4; ++mf) {
        const int y = ybase + 2 * mf + (quad >> 1);
        float or_ = 0.f, oi_ = 0.f;
#pragma unroll
        for (int r = 0; r < 4; ++r) {
            int c = 4 * (quad & 1) + r;
            float sr = csmap[(size_t)c * 2 * NXY * NXY + x * NXY + y];
            float si = csmap[(size_t)c * 2 * NXY * NXY + NXY * NXY + x * NXY + y];
            float xr = accr[mf][r], xi = acci[mf][r];
            or_ += sr * xr + si * xi;
            oi_ += sr * xi - si * xr;
        }
        or_ += __shfl_xor(or_, 16);
        oi_ += __shfl_xor(oi_, 16);
        if ((lane & 16) == 0) {
            out[(size_t)(x * NXY + y) * NT + t] = or_;
            out[(size_t)NXY * NXY * NT + (size_t)(x * NXY + y) * NT + t] = oi_;
        }
    }
}

// ---------------------------------------------------------------------------
extern "C" void kernel_launch(void* const* d_in, const int* in_sizes, int n_in,
                              void* d_out, int out_size, void* d_ws, size_t ws_size,
                              hipStream_t stream) {
    const float* xin   = (const float*)d_in[0];  // (2,128,128,16)
    const float* ktraj = (const float*)d_in[1];  // (2,2048,16)
    const float* csmap = (const float*)d_in[2];  // (8,2,128,128)
    const float* dcomp = (const float*)d_in[3];  // (2048,16)
    float* out = (float*)d_out;                  // (2,128,128,16)

    // ws layout: ExC + ExT + EyL (16MB each) + srcB 8MB + g 2MB = 58MB
    const size_t TBL = (size_t)NT * NK * NXY;            // 4.19M dwords per table
    uint* ExC  = (uint*)d_ws;                            // [t][kt][xc][kp][xq]
    uint* ExT  = ExC + TBL;                              // [t][x][k]
    uint* EyL  = ExT + TBL;                              // [t][k][y]
    uint* srcB = EyL + TBL;                              // fragment-ordered
    float2* g  = (float2*)(srcB + (size_t)NT * NC * NXY * NXY);  // [t][k][c]

    prep_all<<<dim3(40960), 256, 0, stream>>>(ktraj, xin, csmap, ExC, ExT, EyL, srcB);
    fwd_gemm<<<dim3(NT, NC, 32), 256, 0, stream>>>(ExC, EyL, srcB, dcomp, g);
    adj_gemm<<<dim3(NT, NXY / 8), 512, 0, stream>>>(ExT, EyL, g, csmap, out);
}